// Round 5
// baseline (314.792 us; speedup 1.0000x reference)
//
#include <hip/hip_runtime.h>
#include <math.h>

// GAT actor-critic forward on MI355X.
// bf16-MFMA GEMMs, CSR built per-call. Atomic counters (deg/cur) padded to one
// per 128B line (stride 32 ints) to break memory-side same-line atomic chains;
// deg additionally 2-way split per node. Wave-per-node chunk-16 softmax agg.

#define DSTR 32   // counter stride in ints (128 B line)

typedef __attribute__((ext_vector_type(8))) short short8;
typedef __attribute__((ext_vector_type(4))) float floatx4;

__device__ __forceinline__ float leaky02(float e){ return e > 0.f ? e : 0.2f*e; }

// bf16 helpers (RNE)
__device__ __forceinline__ unsigned short f2bf(float f){
    union { float f; unsigned int i; } v; v.f = f;
    unsigned int r = v.i + 0x7fffu + ((v.i >> 16) & 1u);
    return (unsigned short)(r >> 16);
}
__device__ __forceinline__ float bfx(unsigned int g){
    union { unsigned int i; float f; } v; v.i = g << 16; return v.f;
}
__device__ __forceinline__ float bfy(unsigned int g){
    union { unsigned int i; float f; } v; v.i = g & 0xffff0000u; return v.f;
}
__device__ __forceinline__ float bf1(unsigned short u){
    union { unsigned int i; float f; } v; v.i = ((unsigned int)u) << 16; return v.f;
}

// ---------------- prep: transpose+convert weights to bf16 [n][k] ----------------
__global__ void k_prep(const float* __restrict__ W1, const float* __restrict__ W2,
                       unsigned short* __restrict__ w1t, unsigned short* __restrict__ w2t)
{
    int tid = threadIdx.x;
    for (int i = tid; i < 128*128; i += 256){
        int nn = i >> 7, k = i & 127;
        w1t[i] = f2bf(W1[k*128 + nn]);
    }
    for (int i = tid; i < 32*128; i += 256){
        int nn = i >> 7, k = i & 127;
        w2t[i] = f2bf(W2[k*32 + nn]);
    }
}

// ---------------- gemm1 (+ fused padded dst-degree histogram): h1b = bf16(x @ W1) ----------------
__global__ __launch_bounds__(256) void k_gemm1(const float* __restrict__ x,
        const unsigned short* __restrict__ w1t,
        const float* __restrict__ aS, const float* __restrict__ aD,
        unsigned short* __restrict__ h1b, float* __restrict__ pAS, float* __restrict__ pAD, int n,
        const int* __restrict__ ei, int e, int e2, int* __restrict__ degP)
{
    __shared__ unsigned short As[64*136];   // 17.4 KB  [row][k] padded
    __shared__ unsigned short Bs[128*136];  // 34.8 KB  [n][k]  padded
    const int tid  = threadIdx.x;
    const int brow = blockIdx.x*64;

    // fused histogram: padded counters, 2-way split per node to shorten chains
    {
        int g = blockIdx.x*256 + tid;
        int stride = gridDim.x*256;
        int sub = (tid & 1) << 4;          // 0 or 16 (different 64B half-lines)
        for (; g < e2; g += stride){
            int d = (g < e) ? ei[(size_t)e + g] : (g - e);
            atomicAdd(&degP[d*DSTR + sub], 1);
        }
    }

    // stage A: x fp32 -> bf16 LDS
    {
        int row = tid >> 2, cb = (tid & 3)*32;
        bool ok = brow + row < n;
        #pragma unroll
        for (int i=0;i<8;i++){
            float4 v = ok ? *(const float4*)&x[(size_t)(brow+row)*128 + cb + i*4]
                          : make_float4(0.f,0.f,0.f,0.f);
            ushort4 b = make_ushort4(f2bf(v.x),f2bf(v.y),f2bf(v.z),f2bf(v.w));
            *(ushort4*)&As[row*136 + cb + i*4] = b;
        }
    }
    // stage B: w1t bf16 [128][128] -> LDS
    {
        int nn = tid >> 1, kb = (tid & 1)*64;
        #pragma unroll
        for (int i=0;i<8;i++)
            *(uint4*)&Bs[nn*136 + kb + i*8] = *(const uint4*)&w1t[nn*128 + kb + i*8];
    }
    __syncthreads();

    const int wv = tid >> 6, lane = tid & 63;
    const int m = lane & 15, quad = lane >> 4;
    floatx4 acc[8];
    #pragma unroll
    for (int i=0;i<8;i++) acc[i] = (floatx4){0.f,0.f,0.f,0.f};

    #pragma unroll
    for (int kc=0; kc<4; kc++){
        int k0 = kc*32 + quad*8;
        short8 a = *(const short8*)&As[(wv*16+m)*136 + k0];
        #pragma unroll
        for (int ct=0; ct<8; ct++){
            short8 b = *(const short8*)&Bs[(ct*16+m)*136 + k0];
            acc[ct] = __builtin_amdgcn_mfma_f32_16x16x32_bf16(a, b, acc[ct], 0,0,0);
        }
    }
    __syncthreads();   // done reading As

    // repack C (bf16) into As as [64][128]
    #pragma unroll
    for (int ct=0; ct<8; ct++){
        #pragma unroll
        for (int r=0;r<4;r++){
            int row = wv*16 + quad*4 + r;
            As[row*128 + ct*16 + m] = f2bf(acc[ct][r]);
        }
    }
    __syncthreads();

    // coalesced global writes + per-(row,head) attention dots
    {
        int row = tid >> 2, hd = tid & 3;
        int grow = brow + row;
        if (grow < n){
            float ps=0.f, pd=0.f;
            #pragma unroll
            for (int i=0;i<4;i++){
                uint4 u = *(const uint4*)&As[row*128 + hd*32 + i*8];
                *(uint4*)&h1b[(size_t)grow*128 + hd*32 + i*8] = u;
                unsigned int uw[4] = {u.x,u.y,u.z,u.w};
                #pragma unroll
                for (int j=0;j<4;j++){
                    float c0 = bfx(uw[j]), c1 = bfy(uw[j]);
                    int cc = hd*32 + i*8 + j*2;
                    ps += c0*aS[cc] + c1*aS[cc+1];
                    pd += c0*aD[cc] + c1*aD[cc+1];
                }
            }
            pAS[grow*4+hd] = ps;
            pAD[grow*4+hd] = pd;
        }
    }
}

// ---------------- 3-kernel exclusive scan over padded deg -> rs/re/curP ----------------
__global__ void k_scan_local(const int* __restrict__ degP, int* __restrict__ tmp,
                             int* __restrict__ blkSum, int n)
{
    __shared__ int sb[256];
    int tid = threadIdx.x;
    int i = blockIdx.x*256 + tid;
    int v = (i < n) ? (degP[(size_t)i*DSTR] + degP[(size_t)i*DSTR + 16]) : 0;
    sb[tid] = v; __syncthreads();
    for (int off=1; off<256; off<<=1){
        int t = (tid >= off) ? sb[tid-off] : 0;
        __syncthreads();
        if (tid >= off) sb[tid] += t;
        __syncthreads();
    }
    if (i < n) tmp[i] = sb[tid];
    if (tid == 255) blkSum[blockIdx.x] = sb[255];
}

__global__ void k_scan_blk(const int* __restrict__ bs, int* __restrict__ bo, int nb,
                           float* __restrict__ out_val, const float* __restrict__ bc)
{
    __shared__ int sb[256];
    int tid = threadIdx.x;
    if (tid == 0) *out_val = bc[0];
    int v = (tid < nb) ? bs[tid] : 0;
    sb[tid] = v; __syncthreads();
    for (int off=1; off<256; off<<=1){
        int t = (tid >= off) ? sb[tid-off] : 0;
        __syncthreads();
        if (tid >= off) sb[tid] += t;
        __syncthreads();
    }
    if (tid < nb) bo[tid] = sb[tid] - v;
}

__global__ void k_scan_fix(const int* __restrict__ tmp, const int* __restrict__ bo,
                           const int* __restrict__ degP, int* __restrict__ rs,
                           int* __restrict__ re, int* __restrict__ curP, int n)
{
    int i = blockIdx.x*blockDim.x + threadIdx.x;
    if (i < n){
        int G = tmp[i] + bo[i >> 8];
        int d = degP[(size_t)i*DSTR] + degP[(size_t)i*DSTR + 16];
        rs[i]  = G - d;
        curP[(size_t)i*DSTR] = G - d;
        re[i]  = G;
    }
}

// ---------------- scatter edges into CSR (padded cursors) ----------------
__global__ void k_scatter(const int* __restrict__ ei, int e, int e2,
                          int* __restrict__ curP, int* __restrict__ csr)
{
    int g = blockIdx.x*blockDim.x + threadIdx.x;
    if (g < e2){
        int s, d;
        if (g < e){ s = ei[g]; d = ei[(size_t)e + g]; }
        else      { s = g - e; d = g - e; }
        int p = atomicAdd(&curP[(size_t)d*DSTR], 1);
        csr[p] = s;
    }
}

// ---------------- layer-1 aggregation: chunk-16, lane-parallel exp, 16-deep gather ----------------
__global__ __launch_bounds__(256) void k_agg1(const int* __restrict__ rs, const int* __restrict__ re,
        const int* __restrict__ csr, const float* __restrict__ as1, const float* __restrict__ ad1,
        const unsigned short* __restrict__ h1b, const float* __restrict__ b1,
        unsigned short* __restrict__ h1ob, int n)
{
    const int lane = threadIdx.x & 63;
    const int node = blockIdx.x*4 + (threadIdx.x >> 6);
    if (node >= n) return;
    const int h   = lane >> 4;
    const int f   = lane*2;
    const int j16 = lane & 15;
    const int grp = lane & 48;
    const float adv = ad1[node*4 + h];
    const int start = rs[node], end = re[node];
    const unsigned int* hp = (const unsigned int*)h1b + (f >> 1);  // index s*64

    float den = 0.f, ax = 0.f, ay = 0.f;
    int i0 = start;

    for (; i0 + 16 <= end; i0 += 16){
        int sj = csr[i0 + j16];
        float e = __expf(leaky02(as1[sj*4 + h] + adv));
        den += e;
        #pragma unroll
        for (int j = 0; j < 16; j++){
            float ej = __shfl(e,  grp + j, 64);
            int   s2 = __shfl(sj, grp + j, 64);
            unsigned int g = hp[s2*64];
            ax += ej*bfx(g); ay += ej*bfy(g);
        }
    }
    int c = end - i0;
    if (c > 0){
        int jj = (j16 < c) ? j16 : (c-1);
        int sj = csr[i0 + jj];
        float e = __expf(leaky02(as1[sj*4 + h] + adv));
        if (j16 < c) den += e;
        for (int j = 0; j < c; j += 4){
            #pragma unroll
            for (int u = 0; u < 4; u++){
                int je = j + u;
                int jc = (je < c) ? je : (c-1);
                float ej = __shfl(e,  grp + jc, 64);
                int   s2 = __shfl(sj, grp + jc, 64);
                ej = (je < c) ? ej : 0.f;
                unsigned int g = hp[s2*64];
                ax += ej*bfx(g); ay += ej*bfy(g);
            }
        }
    }
    den += __shfl_xor(den, 1, 64);
    den += __shfl_xor(den, 2, 64);
    den += __shfl_xor(den, 4, 64);
    den += __shfl_xor(den, 8, 64);

    float ox = ax/den + b1[f];
    float oy = ay/den + b1[f+1];
    ox = ox > 0.f ? ox : expm1f(ox);
    oy = oy > 0.f ? oy : expm1f(oy);
    unsigned int pk = (unsigned int)f2bf(ox) | ((unsigned int)f2bf(oy) << 16);
    *(unsigned int*)&h1ob[(size_t)node*128 + f] = pk;
}

// ---------------- gemm2 (MFMA): h2pb = bf16(h1ob @ W2); fused a_s/a_d ----------------
__global__ __launch_bounds__(256) void k_gemm2(const unsigned short* __restrict__ h1ob,
        const unsigned short* __restrict__ w2t,
        const float* __restrict__ aS, const float* __restrict__ aD,
        unsigned short* __restrict__ h2pb, float* __restrict__ pAS, float* __restrict__ pAD, int n)
{
    __shared__ unsigned short As[64*136];   // 17.4 KB
    __shared__ unsigned short Bs[32*136];   // 8.7 KB
    const int tid  = threadIdx.x;
    const int brow = blockIdx.x*64;

    {   // stage A (already bf16)
        int row = tid >> 2, cb = (tid & 3)*32;
        bool ok = brow + row < n;
        #pragma unroll
        for (int i=0;i<4;i++){
            uint4 v = ok ? *(const uint4*)&h1ob[(size_t)(brow+row)*128 + cb + i*8]
                         : make_uint4(0,0,0,0);
            *(uint4*)&As[row*136 + cb + i*8] = v;
        }
    }
    {   // stage B: w2t [32][128]
        int nn = tid >> 3, kb = (tid & 7)*16;
        *(uint4*)&Bs[nn*136 + kb]     = *(const uint4*)&w2t[nn*128 + kb];
        *(uint4*)&Bs[nn*136 + kb + 8] = *(const uint4*)&w2t[nn*128 + kb + 8];
    }
    __syncthreads();

    const int wv = tid >> 6, lane = tid & 63;
    const int m = lane & 15, quad = lane >> 4;
    floatx4 acc[2];
    acc[0] = (floatx4){0.f,0.f,0.f,0.f};
    acc[1] = (floatx4){0.f,0.f,0.f,0.f};

    #pragma unroll
    for (int kc=0; kc<4; kc++){
        int k0 = kc*32 + quad*8;
        short8 a = *(const short8*)&As[(wv*16+m)*136 + k0];
        #pragma unroll
        for (int ct=0; ct<2; ct++){
            short8 b = *(const short8*)&Bs[(ct*16+m)*136 + k0];
            acc[ct] = __builtin_amdgcn_mfma_f32_16x16x32_bf16(a, b, acc[ct], 0,0,0);
        }
    }
    __syncthreads();

    #pragma unroll
    for (int ct=0; ct<2; ct++){
        #pragma unroll
        for (int r=0;r<4;r++){
            int row = wv*16 + quad*4 + r;
            As[row*32 + ct*16 + m] = f2bf(acc[ct][r]);
        }
    }
    __syncthreads();

    if (tid < 64){
        int grow = brow + tid;
        if (grow < n){
            float ps=0.f, pd=0.f;
            #pragma unroll
            for (int i=0;i<4;i++){
                uint4 u = *(const uint4*)&As[tid*32 + i*8];
                *(uint4*)&h2pb[(size_t)grow*32 + i*8] = u;
                unsigned int uw[4] = {u.x,u.y,u.z,u.w};
                #pragma unroll
                for (int j=0;j<4;j++){
                    float c0 = bfx(uw[j]), c1 = bfy(uw[j]);
                    int cc = i*8 + j*2;
                    ps += c0*aS[cc] + c1*aS[cc+1];
                    pd += c0*aD[cc] + c1*aD[cc+1];
                }
            }
            pAS[grow] = ps;
            pAD[grow] = pd;
        }
    }
}

// ---------------- layer-2 aggregation: chunk-16, halves split payload edges ----------------
__global__ __launch_bounds__(256) void k_agg2(const int* __restrict__ rs, const int* __restrict__ re,
        const int* __restrict__ csr, const float* __restrict__ as2, const float* __restrict__ ad2,
        const unsigned short* __restrict__ h2pb, const float* __restrict__ b2,
        float* __restrict__ out, int n)
{
    const int lane = threadIdx.x & 63;
    const int node = blockIdx.x*4 + (threadIdx.x >> 6);
    if (node >= n) return;
    const int f    = lane & 31;
    const int half = lane >> 5;
    const int j16  = lane & 15;
    const int grp  = lane & 48;
    const float adv = ad2[node];
    const int start = rs[node], end = re[node];
    const unsigned short* hp = h2pb + f;

    float den = 0.f, acc = 0.f;
    int i0 = start;

    for (; i0 + 16 <= end; i0 += 16){
        int sj = csr[i0 + j16];
        float e = __expf(leaky02(as2[sj] + adv));
        den += e;
        #pragma unroll
        for (int jj = 0; jj < 8; jj++){
            int j = 2*jj + half;
            float ej = __shfl(e,  grp + j, 64);
            int   s2 = __shfl(sj, grp + j, 64);
            acc += ej * bf1(hp[s2*32]);
        }
    }
    int c = end - i0;
    if (c > 0){
        int jj = (j16 < c) ? j16 : (c-1);
        int sj = csr[i0 + jj];
        float e = __expf(leaky02(as2[sj] + adv));
        if (j16 < c) den += e;
        for (int j = half; j < c; j += 8){
            #pragma unroll
            for (int u = 0; u < 4; u++){
                int je = j + 2*u;
                int jc = (je < c) ? je : (c-1);
                float ej = __shfl(e,  grp + (jc & 15), 64);
                int   s2 = __shfl(sj, grp + (jc & 15), 64);
                ej = (je < c) ? ej : 0.f;
                acc += ej * bf1(hp[s2*32]);
            }
        }
    }
    den += __shfl_xor(den, 1, 64);
    den += __shfl_xor(den, 2, 64);
    den += __shfl_xor(den, 4, 64);
    den += __shfl_xor(den, 8, 64);
    acc += __shfl_xor(acc, 32, 64);

    if (half == 0){
        float o = acc/den + b2[f];
        o = o > 0.f ? o : expm1f(o);
        out[(size_t)node*32 + f] = o;
    }
}

// ---------------- heads: logits[A,N] (transposed store) + value mean ----------------
__global__ __launch_bounds__(256) void k_head(const float* __restrict__ h2, const float* __restrict__ Wa,
        const float* __restrict__ ba, const float* __restrict__ Wc, int n, float* __restrict__ out)
{
    __shared__ float WaS[1024];
    __shared__ float baS[32], WcS[32];
    int tid = threadIdx.x;
    *(float4*)&WaS[tid*4] = *(const float4*)&Wa[tid*4];
    if (tid < 32){ baS[tid] = ba[tid]; WcS[tid] = Wc[tid]; }
    __syncthreads();

    int nidx = blockIdx.x*256 + tid;
    bool act = nidx < n;
    float hv[32];
    #pragma unroll
    for (int j=0;j<8;j++){
        float4 v = act ? *(const float4*)&h2[(size_t)nidx*32 + j*4] : make_float4(0.f,0.f,0.f,0.f);
        hv[j*4+0]=v.x; hv[j*4+1]=v.y; hv[j*4+2]=v.z; hv[j*4+3]=v.w;
    }
    #pragma unroll
    for (int a=0;a<32;a++){
        float acc = baS[a];
        #pragma unroll
        for (int c=0;c<32;c++) acc += hv[c]*WaS[c*32+a];
        if (act) out[(size_t)a*n + nidx] = acc;
    }
    float v = 0.f;
    #pragma unroll
    for (int c=0;c<32;c++) v += hv[c]*WcS[c];
    #pragma unroll
    for (int msk=1; msk<64; msk<<=1) v += __shfl_xor(v, msk, 64);
    if ((tid & 63) == 0) atomicAdd(&out[(size_t)32*n], v*(1.0f/n));
}

extern "C" void kernel_launch(void* const* d_in, const int* in_sizes, int n_in,
                              void* d_out, int out_size, void* d_ws, size_t ws_size,
                              hipStream_t stream)
{
    const float* x   = (const float*)d_in[0];
    const int*   ei  = (const int*)d_in[1];
    const float* W1  = (const float*)d_in[2];
    const float* a1s = (const float*)d_in[3];
    const float* a1d = (const float*)d_in[4];
    const float* b1  = (const float*)d_in[5];
    const float* W2  = (const float*)d_in[6];
    const float* a2s = (const float*)d_in[7];
    const float* a2d = (const float*)d_in[8];
    const float* b2  = (const float*)d_in[9];
    const float* Wa  = (const float*)d_in[10];
    const float* ba  = (const float*)d_in[11];
    const float* Wc  = (const float*)d_in[12];
    const float* bc  = (const float*)d_in[13];
    float* out = (float*)d_out;

    const int N  = in_sizes[0] / 128;
    const int E  = in_sizes[1] / 2;
    const int E2 = E + N;

    // workspace layout (256B-aligned chunks)
    char* base = (char*)d_ws;
    auto alloc = [&](size_t bytes) -> char* {
        char* p = base; base += (bytes + 255) & ~(size_t)255; return p;
    };
    float* h2   = (float*)alloc((size_t)N*32*4);
    float* as1  = (float*)alloc((size_t)N*4*4);
    float* ad1  = (float*)alloc((size_t)N*4*4);
    float* as2  = (float*)alloc((size_t)N*4);
    float* ad2  = (float*)alloc((size_t)N*4);
    int* degP   = (int*)alloc((size_t)N*DSTR*4);   // padded: 1 line / node
    int* curP   = (int*)alloc((size_t)N*DSTR*4);   // padded cursors
    int* tmp    = (int*)alloc((size_t)N*4);
    int* blkSum = (int*)alloc(1024);
    int* blkOff = (int*)alloc(1024);
    int* rs     = (int*)alloc((size_t)N*4);
    int* re     = (int*)alloc((size_t)N*4);
    int* csr    = (int*)alloc((size_t)E2*4);
    unsigned short* h1b  = (unsigned short*)alloc((size_t)N*128*2);
    unsigned short* h1ob = (unsigned short*)alloc((size_t)N*128*2);
    unsigned short* h2pb = (unsigned short*)alloc((size_t)N*32*2);
    unsigned short* w1t  = (unsigned short*)alloc(128*128*2);
    unsigned short* w2t  = (unsigned short*)alloc(32*128*2);

    const int nbN   = (N + 255) / 256;
    const int nbE   = (E2 + 255) / 256;
    const int nbG   = (N + 63) / 64;
    const int nbAgg = (N + 3) / 4;

    hipMemsetAsync(degP, 0, (size_t)N*DSTR*4, stream);
    k_prep<<<1, 256, 0, stream>>>(W1, W2, w1t, w2t);
    k_gemm1<<<nbG, 256, 0, stream>>>(x, w1t, a1s, a1d, h1b, as1, ad1, N, ei, E, E2, degP);
    k_scan_local<<<nbN, 256, 0, stream>>>(degP, tmp, blkSum, N);
    k_scan_blk<<<1, 256, 0, stream>>>(blkSum, blkOff, nbN, out + (size_t)32*N, bc);
    k_scan_fix<<<nbN, 256, 0, stream>>>(tmp, blkOff, degP, rs, re, curP, N);
    k_scatter<<<nbE, 256, 0, stream>>>(ei, E, E2, curP, csr);
    k_agg1<<<nbAgg, 256, 0, stream>>>(rs, re, csr, as1, ad1, h1b, b1, h1ob, N);
    k_gemm2<<<nbG, 256, 0, stream>>>(h1ob, w2t, a2s, a2d, h2pb, as2, ad2, N);
    k_agg2<<<nbAgg, 256, 0, stream>>>(rs, re, csr, as2, ad2, h2pb, b2, h2, N);
    k_head<<<nbN, 256, 0, stream>>>(h2, Wa, ba, Wc, N, out);
}

// Round 6
// 293.702 us; speedup vs baseline: 1.0718x; 1.0718x over previous
//
#include <hip/hip_runtime.h>
#include <math.h>

// GAT actor-critic forward on MI355X.
// CSR via atomic-free two-phase bucket sort (LDS histograms + precomputed
// chunk offsets; only LDS atomics). bf16-MFMA GEMMs. Wave-per-node chunk-16
// softmax aggregation with bf16 payloads, fp32 accumulation.

#define TILE 4096   // edges per count/bucket block

typedef __attribute__((ext_vector_type(8))) short short8;
typedef __attribute__((ext_vector_type(4))) float floatx4;

__device__ __forceinline__ float leaky02(float e){ return e > 0.f ? e : 0.2f*e; }

// bf16 helpers (RNE)
__device__ __forceinline__ unsigned short f2bf(float f){
    union { float f; unsigned int i; } v; v.f = f;
    unsigned int r = v.i + 0x7fffu + ((v.i >> 16) & 1u);
    return (unsigned short)(r >> 16);
}
__device__ __forceinline__ float bfx(unsigned int g){
    union { unsigned int i; float f; } v; v.i = g << 16; return v.f;
}
__device__ __forceinline__ float bfy(unsigned int g){
    union { unsigned int i; float f; } v; v.i = g & 0xffff0000u; return v.f;
}
__device__ __forceinline__ float bf1(unsigned short u){
    union { unsigned int i; float f; } v; v.i = ((unsigned int)u) << 16; return v.f;
}

// ---------------- prep: transpose+convert weights to bf16 [n][k] ----------------
__global__ void k_prep(const float* __restrict__ W1, const float* __restrict__ W2,
                       unsigned short* __restrict__ w1t, unsigned short* __restrict__ w2t)
{
    int tid = threadIdx.x;
    for (int i = tid; i < 128*128; i += 256){
        int nn = i >> 7, k = i & 127;
        w1t[i] = f2bf(W1[k*128 + nn]);
    }
    for (int i = tid; i < 32*128; i += 256){
        int nn = i >> 7, k = i & 127;
        w2t[i] = f2bf(W2[k*32 + nn]);
    }
}

// ---------------- sort pass A: per-tile high-digit histogram (LDS only) ----------------
__global__ __launch_bounds__(256) void k_cnt(const int* __restrict__ ei, int e, int e2,
                                             int* __restrict__ counts)
{
    __shared__ int h[256];
    int t = threadIdx.x;
    h[t] = 0; __syncthreads();
    int base = blockIdx.x*TILE;
    #pragma unroll
    for (int k = 0; k < TILE/256; k++){
        int i = base + k*256 + t;
        if (i < e2){
            int d = (i < e) ? ei[(size_t)e + i] : (i - e);
            atomicAdd(&h[d >> 8], 1);
        }
    }
    __syncthreads();
    counts[blockIdx.x*256 + t] = h[t];
}

// ---------------- sort pass B: offsets (in-place over counts) + bucket bases ----------------
__global__ void k_base(int* __restrict__ counts, int nb, int* __restrict__ base257,
                       float* __restrict__ out_val, const float* __restrict__ bc)
{
    __shared__ int sb[256];
    int t = threadIdx.x;
    if (t == 0) *out_val = bc[0];
    int running = 0;
    for (int b = 0; b < nb; b++){
        int c = counts[b*256 + t];
        counts[b*256 + t] = running;     // exclusive prefix within digit
        running += c;
    }
    sb[t] = running; __syncthreads();
    for (int off = 1; off < 256; off <<= 1){
        int v = (t >= off) ? sb[t-off] : 0;
        __syncthreads();
        if (t >= off) sb[t] += v;
        __syncthreads();
    }
    base257[t] = sb[t] - running;        // digit/bucket start
    if (t == 255) base257[256] = sb[t];
}

// ---------------- sort pass C: scatter into buckets (LDS cursors, no global atomics) ----------------
__global__ __launch_bounds__(256) void k_bucket(const int* __restrict__ ei, int e, int e2,
        const int* __restrict__ counts, const int* __restrict__ base257,
        unsigned int* __restrict__ buck)
{
    __shared__ int curs[256];
    int t = threadIdx.x;
    curs[t] = counts[blockIdx.x*256 + t] + base257[t];
    __syncthreads();
    int base = blockIdx.x*TILE;
    #pragma unroll
    for (int k = 0; k < TILE/256; k++){
        int i = base + k*256 + t;
        if (i < e2){
            int s, d;
            if (i < e){ s = ei[i]; d = ei[(size_t)e + i]; }
            else      { s = i - e; d = i - e; }
            int p = atomicAdd(&curs[d >> 8], 1);
            buck[p] = ((unsigned int)d << 16) | (unsigned int)s;
        }
    }
}

// ---------------- sort pass D: per-bucket counting sort -> csr + rs/re ----------------
__global__ __launch_bounds__(256) void k_p2(const unsigned int* __restrict__ buck,
        const int* __restrict__ base257, int n,
        int* __restrict__ csr, int* __restrict__ rs, int* __restrict__ re)
{
    __shared__ int bins[256], sc[256], curs[256];
    const int b = blockIdx.x, t = threadIdx.x;
    const int lo = base257[b], hi = base257[b+1];
    bins[t] = 0; __syncthreads();
    for (int i = lo + t; i < hi; i += 256){
        int dg = (buck[i] >> 16) & 0xFF;
        atomicAdd(&bins[dg], 1);
    }
    __syncthreads();
    sc[t] = bins[t]; __syncthreads();
    for (int off = 1; off < 256; off <<= 1){
        int v = (t >= off) ? sc[t-off] : 0;
        __syncthreads();
        if (t >= off) sc[t] += v;
        __syncthreads();
    }
    int sInc = sc[t];
    int node = b*256 + t;
    if (node < n){
        rs[node] = lo + sInc - bins[t];
        re[node] = lo + sInc;
    }
    curs[t] = lo + sInc - bins[t];
    __syncthreads();
    for (int i = lo + t; i < hi; i += 256){
        unsigned int pk = buck[i];
        int p = atomicAdd(&curs[(pk >> 16) & 0xFF], 1);
        csr[p] = (int)(pk & 0xFFFFu);
    }
}

// ---------------- gemm1 (pure MFMA): h1b = bf16(x @ W1); fused a_s/a_d dots ----------------
__global__ __launch_bounds__(256) void k_gemm1(const float* __restrict__ x,
        const unsigned short* __restrict__ w1t,
        const float* __restrict__ aS, const float* __restrict__ aD,
        unsigned short* __restrict__ h1b, float* __restrict__ pAS, float* __restrict__ pAD, int n)
{
    __shared__ unsigned short As[64*136];   // 17.4 KB  [row][k] padded
    __shared__ unsigned short Bs[128*136];  // 34.8 KB  [n][k]  padded
    const int tid  = threadIdx.x;
    const int brow = blockIdx.x*64;

    // stage A: x fp32 -> bf16 LDS
    {
        int row = tid >> 2, cb = (tid & 3)*32;
        bool ok = brow + row < n;
        #pragma unroll
        for (int i=0;i<8;i++){
            float4 v = ok ? *(const float4*)&x[(size_t)(brow+row)*128 + cb + i*4]
                          : make_float4(0.f,0.f,0.f,0.f);
            ushort4 b = make_ushort4(f2bf(v.x),f2bf(v.y),f2bf(v.z),f2bf(v.w));
            *(ushort4*)&As[row*136 + cb + i*4] = b;
        }
    }
    // stage B: w1t bf16 [128][128] -> LDS
    {
        int nn = tid >> 1, kb = (tid & 1)*64;
        #pragma unroll
        for (int i=0;i<8;i++)
            *(uint4*)&Bs[nn*136 + kb + i*8] = *(const uint4*)&w1t[nn*128 + kb + i*8];
    }
    __syncthreads();

    const int wv = tid >> 6, lane = tid & 63;
    const int m = lane & 15, quad = lane >> 4;
    floatx4 acc[8];
    #pragma unroll
    for (int i=0;i<8;i++) acc[i] = (floatx4){0.f,0.f,0.f,0.f};

    #pragma unroll
    for (int kc=0; kc<4; kc++){
        int k0 = kc*32 + quad*8;
        short8 a = *(const short8*)&As[(wv*16+m)*136 + k0];
        #pragma unroll
        for (int ct=0; ct<8; ct++){
            short8 b = *(const short8*)&Bs[(ct*16+m)*136 + k0];
            acc[ct] = __builtin_amdgcn_mfma_f32_16x16x32_bf16(a, b, acc[ct], 0,0,0);
        }
    }
    __syncthreads();   // done reading As

    // repack C (bf16) into As as [64][128]
    #pragma unroll
    for (int ct=0; ct<8; ct++){
        #pragma unroll
        for (int r=0;r<4;r++){
            int row = wv*16 + quad*4 + r;
            As[row*128 + ct*16 + m] = f2bf(acc[ct][r]);
        }
    }
    __syncthreads();

    // coalesced global writes + per-(row,head) attention dots
    {
        int row = tid >> 2, hd = tid & 3;
        int grow = brow + row;
        if (grow < n){
            float ps=0.f, pd=0.f;
            #pragma unroll
            for (int i=0;i<4;i++){
                uint4 u = *(const uint4*)&As[row*128 + hd*32 + i*8];
                *(uint4*)&h1b[(size_t)grow*128 + hd*32 + i*8] = u;
                unsigned int uw[4] = {u.x,u.y,u.z,u.w};
                #pragma unroll
                for (int j=0;j<4;j++){
                    float c0 = bfx(uw[j]), c1 = bfy(uw[j]);
                    int cc = hd*32 + i*8 + j*2;
                    ps += c0*aS[cc] + c1*aS[cc+1];
                    pd += c0*aD[cc] + c1*aD[cc+1];
                }
            }
            pAS[grow*4+hd] = ps;
            pAD[grow*4+hd] = pd;
        }
    }
}

// ---------------- layer-1 aggregation: chunk-16, lane-parallel exp, 16-deep gather ----------------
__global__ __launch_bounds__(256) void k_agg1(const int* __restrict__ rs, const int* __restrict__ re,
        const int* __restrict__ csr, const float* __restrict__ as1, const float* __restrict__ ad1,
        const unsigned short* __restrict__ h1b, const float* __restrict__ b1,
        unsigned short* __restrict__ h1ob, int n)
{
    const int lane = threadIdx.x & 63;
    const int node = blockIdx.x*4 + (threadIdx.x >> 6);
    if (node >= n) return;
    const int h   = lane >> 4;
    const int f   = lane*2;
    const int j16 = lane & 15;
    const int grp = lane & 48;
    const float adv = ad1[node*4 + h];
    const int start = rs[node], end = re[node];
    const unsigned int* hp = (const unsigned int*)h1b + (f >> 1);  // index s*64

    float den = 0.f, ax = 0.f, ay = 0.f;
    int i0 = start;

    for (; i0 + 16 <= end; i0 += 16){
        int sj = csr[i0 + j16];
        float e = __expf(leaky02(as1[sj*4 + h] + adv));
        den += e;
        #pragma unroll
        for (int j = 0; j < 16; j++){
            float ej = __shfl(e,  grp + j, 64);
            int   s2 = __shfl(sj, grp + j, 64);
            unsigned int g = hp[s2*64];
            ax += ej*bfx(g); ay += ej*bfy(g);
        }
    }
    int c = end - i0;
    if (c > 0){
        int jj = (j16 < c) ? j16 : (c-1);
        int sj = csr[i0 + jj];
        float e = __expf(leaky02(as1[sj*4 + h] + adv));
        if (j16 < c) den += e;
        for (int j = 0; j < c; j += 4){
            #pragma unroll
            for (int u = 0; u < 4; u++){
                int je = j + u;
                int jc = (je < c) ? je : (c-1);
                float ej = __shfl(e,  grp + jc, 64);
                int   s2 = __shfl(sj, grp + jc, 64);
                ej = (je < c) ? ej : 0.f;
                unsigned int g = hp[s2*64];
                ax += ej*bfx(g); ay += ej*bfy(g);
            }
        }
    }
    den += __shfl_xor(den, 1, 64);
    den += __shfl_xor(den, 2, 64);
    den += __shfl_xor(den, 4, 64);
    den += __shfl_xor(den, 8, 64);

    float ox = ax/den + b1[f];
    float oy = ay/den + b1[f+1];
    ox = ox > 0.f ? ox : expm1f(ox);
    oy = oy > 0.f ? oy : expm1f(oy);
    unsigned int pk = (unsigned int)f2bf(ox) | ((unsigned int)f2bf(oy) << 16);
    *(unsigned int*)&h1ob[(size_t)node*128 + f] = pk;
}

// ---------------- gemm2 (MFMA): h2pb = bf16(h1ob @ W2); fused a_s/a_d ----------------
__global__ __launch_bounds__(256) void k_gemm2(const unsigned short* __restrict__ h1ob,
        const unsigned short* __restrict__ w2t,
        const float* __restrict__ aS, const float* __restrict__ aD,
        unsigned short* __restrict__ h2pb, float* __restrict__ pAS, float* __restrict__ pAD, int n)
{
    __shared__ unsigned short As[64*136];   // 17.4 KB
    __shared__ unsigned short Bs[32*136];   // 8.7 KB
    const int tid  = threadIdx.x;
    const int brow = blockIdx.x*64;

    {   // stage A (already bf16)
        int row = tid >> 2, cb = (tid & 3)*32;
        bool ok = brow + row < n;
        #pragma unroll
        for (int i=0;i<4;i++){
            uint4 v = ok ? *(const uint4*)&h1ob[(size_t)(brow+row)*128 + cb + i*8]
                         : make_uint4(0,0,0,0);
            *(uint4*)&As[row*136 + cb + i*8] = v;
        }
    }
    {   // stage B: w2t [32][128]
        int nn = tid >> 3, kb = (tid & 7)*16;
        *(uint4*)&Bs[nn*136 + kb]     = *(const uint4*)&w2t[nn*128 + kb];
        *(uint4*)&Bs[nn*136 + kb + 8] = *(const uint4*)&w2t[nn*128 + kb + 8];
    }
    __syncthreads();

    const int wv = tid >> 6, lane = tid & 63;
    const int m = lane & 15, quad = lane >> 4;
    floatx4 acc[2];
    acc[0] = (floatx4){0.f,0.f,0.f,0.f};
    acc[1] = (floatx4){0.f,0.f,0.f,0.f};

    #pragma unroll
    for (int kc=0; kc<4; kc++){
        int k0 = kc*32 + quad*8;
        short8 a = *(const short8*)&As[(wv*16+m)*136 + k0];
        #pragma unroll
        for (int ct=0; ct<2; ct++){
            short8 b = *(const short8*)&Bs[(ct*16+m)*136 + k0];
            acc[ct] = __builtin_amdgcn_mfma_f32_16x16x32_bf16(a, b, acc[ct], 0,0,0);
        }
    }
    __syncthreads();

    #pragma unroll
    for (int ct=0; ct<2; ct++){
        #pragma unroll
        for (int r=0;r<4;r++){
            int row = wv*16 + quad*4 + r;
            As[row*32 + ct*16 + m] = f2bf(acc[ct][r]);
        }
    }
    __syncthreads();

    if (tid < 64){
        int grow = brow + tid;
        if (grow < n){
            float ps=0.f, pd=0.f;
            #pragma unroll
            for (int i=0;i<4;i++){
                uint4 u = *(const uint4*)&As[tid*32 + i*8];
                *(uint4*)&h2pb[(size_t)grow*32 + i*8] = u;
                unsigned int uw[4] = {u.x,u.y,u.z,u.w};
                #pragma unroll
                for (int j=0;j<4;j++){
                    float c0 = bfx(uw[j]), c1 = bfy(uw[j]);
                    int cc = i*8 + j*2;
                    ps += c0*aS[cc] + c1*aS[cc+1];
                    pd += c0*aD[cc] + c1*aD[cc+1];
                }
            }
            pAS[grow] = ps;
            pAD[grow] = pd;
        }
    }
}

// ---------------- layer-2 aggregation: chunk-16, halves split payload edges ----------------
__global__ __launch_bounds__(256) void k_agg2(const int* __restrict__ rs, const int* __restrict__ re,
        const int* __restrict__ csr, const float* __restrict__ as2, const float* __restrict__ ad2,
        const unsigned short* __restrict__ h2pb, const float* __restrict__ b2,
        float* __restrict__ out, int n)
{
    const int lane = threadIdx.x & 63;
    const int node = blockIdx.x*4 + (threadIdx.x >> 6);
    if (node >= n) return;
    const int f    = lane & 31;
    const int half = lane >> 5;
    const int j16  = lane & 15;
    const int grp  = lane & 48;
    const float adv = ad2[node];
    const int start = rs[node], end = re[node];
    const unsigned short* hp = h2pb + f;

    float den = 0.f, acc = 0.f;
    int i0 = start;

    for (; i0 + 16 <= end; i0 += 16){
        int sj = csr[i0 + j16];
        float e = __expf(leaky02(as2[sj] + adv));
        den += e;
        #pragma unroll
        for (int jj = 0; jj < 8; jj++){
            int j = 2*jj + half;
            float ej = __shfl(e,  grp + j, 64);
            int   s2 = __shfl(sj, grp + j, 64);
            acc += ej * bf1(hp[s2*32]);
        }
    }
    int c = end - i0;
    if (c > 0){
        int jj = (j16 < c) ? j16 : (c-1);
        int sj = csr[i0 + jj];
        float e = __expf(leaky02(as2[sj] + adv));
        if (j16 < c) den += e;
        for (int j = half; j < c; j += 8){
            #pragma unroll
            for (int u = 0; u < 4; u++){
                int je = j + 2*u;
                int jc = (je < c) ? je : (c-1);
                float ej = __shfl(e,  grp + (jc & 15), 64);
                int   s2 = __shfl(sj, grp + (jc & 15), 64);
                ej = (je < c) ? ej : 0.f;
                acc += ej * bf1(hp[s2*32]);
            }
        }
    }
    den += __shfl_xor(den, 1, 64);
    den += __shfl_xor(den, 2, 64);
    den += __shfl_xor(den, 4, 64);
    den += __shfl_xor(den, 8, 64);
    acc += __shfl_xor(acc, 32, 64);

    if (half == 0){
        float o = acc/den + b2[f];
        o = o > 0.f ? o : expm1f(o);
        out[(size_t)node*32 + f] = o;
    }
}

// ---------------- heads: logits[A,N] (transposed store) + value mean ----------------
__global__ __launch_bounds__(256) void k_head(const float* __restrict__ h2, const float* __restrict__ Wa,
        const float* __restrict__ ba, const float* __restrict__ Wc, int n, float* __restrict__ out)
{
    __shared__ float WaS[1024];
    __shared__ float baS[32], WcS[32];
    int tid = threadIdx.x;
    *(float4*)&WaS[tid*4] = *(const float4*)&Wa[tid*4];
    if (tid < 32){ baS[tid] = ba[tid]; WcS[tid] = Wc[tid]; }
    __syncthreads();

    int nidx = blockIdx.x*256 + tid;
    bool act = nidx < n;
    float hv[32];
    #pragma unroll
    for (int j=0;j<8;j++){
        float4 v = act ? *(const float4*)&h2[(size_t)nidx*32 + j*4] : make_float4(0.f,0.f,0.f,0.f);
        hv[j*4+0]=v.x; hv[j*4+1]=v.y; hv[j*4+2]=v.z; hv[j*4+3]=v.w;
    }
    #pragma unroll
    for (int a=0;a<32;a++){
        float acc = baS[a];
        #pragma unroll
        for (int c=0;c<32;c++) acc += hv[c]*WaS[c*32+a];
        if (act) out[(size_t)a*n + nidx] = acc;
    }
    float v = 0.f;
    #pragma unroll
    for (int c=0;c<32;c++) v += hv[c]*WcS[c];
    #pragma unroll
    for (int msk=1; msk<64; msk<<=1) v += __shfl_xor(v, msk, 64);
    if ((tid & 63) == 0) atomicAdd(&out[(size_t)32*n], v*(1.0f/n));
}

extern "C" void kernel_launch(void* const* d_in, const int* in_sizes, int n_in,
                              void* d_out, int out_size, void* d_ws, size_t ws_size,
                              hipStream_t stream)
{
    const float* x   = (const float*)d_in[0];
    const int*   ei  = (const int*)d_in[1];
    const float* W1  = (const float*)d_in[2];
    const float* a1s = (const float*)d_in[3];
    const float* a1d = (const float*)d_in[4];
    const float* b1  = (const float*)d_in[5];
    const float* W2  = (const float*)d_in[6];
    const float* a2s = (const float*)d_in[7];
    const float* a2d = (const float*)d_in[8];
    const float* b2  = (const float*)d_in[9];
    const float* Wa  = (const float*)d_in[10];
    const float* ba  = (const float*)d_in[11];
    const float* Wc  = (const float*)d_in[12];
    const float* bc  = (const float*)d_in[13];
    float* out = (float*)d_out;

    const int N  = in_sizes[0] / 128;
    const int E  = in_sizes[1] / 2;
    const int E2 = E + N;
    const int nbT = (E2 + TILE - 1) / TILE;   // sort tiles
    const int nbB = (N + 255) / 256;          // buckets

    // workspace layout (256B-aligned chunks)
    char* base = (char*)d_ws;
    auto alloc = [&](size_t bytes) -> char* {
        char* p = base; base += (bytes + 255) & ~(size_t)255; return p;
    };
    float* h2     = (float*)alloc((size_t)N*32*4);
    float* as1    = (float*)alloc((size_t)N*4*4);
    float* ad1    = (float*)alloc((size_t)N*4*4);
    float* as2    = (float*)alloc((size_t)N*4);
    float* ad2    = (float*)alloc((size_t)N*4);
    int* counts   = (int*)alloc((size_t)nbT*256*4);
    int* base257  = (int*)alloc(257*4);
    int* rs       = (int*)alloc((size_t)N*4);
    int* re       = (int*)alloc((size_t)N*4);
    int* csr      = (int*)alloc((size_t)E2*4);
    unsigned int* buck = (unsigned int*)alloc((size_t)E2*4);
    unsigned short* h1b  = (unsigned short*)alloc((size_t)N*128*2);
    unsigned short* h1ob = (unsigned short*)alloc((size_t)N*128*2);
    unsigned short* h2pb = (unsigned short*)alloc((size_t)N*32*2);
    unsigned short* w1t  = (unsigned short*)alloc(128*128*2);
    unsigned short* w2t  = (unsigned short*)alloc(32*128*2);

    const int nbN   = (N + 255) / 256;
    const int nbG   = (N + 63) / 64;
    const int nbAgg = (N + 3) / 4;

    k_prep<<<1, 256, 0, stream>>>(W1, W2, w1t, w2t);
    k_cnt<<<nbT, 256, 0, stream>>>(ei, E, E2, counts);
    k_base<<<1, 256, 0, stream>>>(counts, nbT, base257, out + (size_t)32*N, bc);
    k_bucket<<<nbT, 256, 0, stream>>>(ei, E, E2, counts, base257, buck);
    k_p2<<<nbB, 256, 0, stream>>>(buck, base257, N, csr, rs, re);
    k_gemm1<<<nbG, 256, 0, stream>>>(x, w1t, a1s, a1d, h1b, as1, ad1, N);
    k_agg1<<<nbAgg, 256, 0, stream>>>(rs, re, csr, as1, ad1, h1b, b1, h1ob, N);
    k_gemm2<<<nbG, 256, 0, stream>>>(h1ob, w2t, a2s, a2d, h2pb, as2, ad2, N);
    k_agg2<<<nbAgg, 256, 0, stream>>>(rs, re, csr, as2, ad2, h2pb, b2, h2, N);
    k_head<<<nbN, 256, 0, stream>>>(h2, Wa, ba, Wc, N, out);
}

// Round 7
// 250.594 us; speedup vs baseline: 1.2562x; 1.1720x over previous
//
#include <hip/hip_runtime.h>
#include <math.h>

// GAT actor-critic forward on MI355X.
// CSR via atomic-free two-phase bucket sort (LDS histograms, transposed counts,
// digit-parallel scan). bf16-MFMA GEMMs. Wave-per-node chunk-16 softmax
// aggregation with bf16 payloads, fp32 accumulation.

#define TILE 4096   // edges per count/bucket block

typedef __attribute__((ext_vector_type(8))) short short8;
typedef __attribute__((ext_vector_type(4))) float floatx4;

__device__ __forceinline__ float leaky02(float e){ return e > 0.f ? e : 0.2f*e; }

// bf16 helpers (RNE)
__device__ __forceinline__ unsigned short f2bf(float f){
    union { float f; unsigned int i; } v; v.f = f;
    unsigned int r = v.i + 0x7fffu + ((v.i >> 16) & 1u);
    return (unsigned short)(r >> 16);
}
__device__ __forceinline__ float bfx(unsigned int g){
    union { unsigned int i; float f; } v; v.i = g << 16; return v.f;
}
__device__ __forceinline__ float bfy(unsigned int g){
    union { unsigned int i; float f; } v; v.i = g & 0xffff0000u; return v.f;
}
__device__ __forceinline__ float bf1(unsigned short u){
    union { unsigned int i; float f; } v; v.i = ((unsigned int)u) << 16; return v.f;
}

// ---------------- prep: transpose+convert weights to bf16 [n][k] ----------------
__global__ void k_prep(const float* __restrict__ W1, const float* __restrict__ W2,
                       unsigned short* __restrict__ w1t, unsigned short* __restrict__ w2t)
{
    int tid = threadIdx.x;
    for (int i = tid; i < 128*128; i += 256){
        int nn = i >> 7, k = i & 127;
        w1t[i] = f2bf(W1[k*128 + nn]);
    }
    for (int i = tid; i < 32*128; i += 256){
        int nn = i >> 7, k = i & 127;
        w2t[i] = f2bf(W2[k*32 + nn]);
    }
}

// ---------------- sort pass A: per-tile high-digit histogram (transposed out) ----------------
__global__ __launch_bounds__(256) void k_cnt(const int* __restrict__ ei, int e, int e2,
                                             int* __restrict__ counts, int nbT)
{
    __shared__ int h[256];
    int t = threadIdx.x;
    h[t] = 0; __syncthreads();
    int base = blockIdx.x*TILE;
    #pragma unroll
    for (int k = 0; k < TILE/256; k++){
        int i = base + k*256 + t;
        if (i < e2){
            int d = (i < e) ? ei[(size_t)e + i] : (i - e);
            atomicAdd(&h[d >> 8], 1);
        }
    }
    __syncthreads();
    counts[(size_t)t*nbT + blockIdx.x] = h[t];   // transposed: [digit][block]
}

// ---------------- sort pass B1: per-digit scan over blocks (256 blocks) ----------------
__global__ __launch_bounds__(256) void k_scan_digit(int* __restrict__ counts, int nb,
                                                    int* __restrict__ digTot)
{
    __shared__ int sb[256];
    const int t = blockIdx.x;       // digit
    const int i = threadIdx.x;
    int carry = 0;
    for (int c0 = 0; c0 < nb; c0 += 256){
        int idx = c0 + i;
        int v = (idx < nb) ? counts[(size_t)t*nb + idx] : 0;
        sb[i] = v; __syncthreads();
        for (int off = 1; off < 256; off <<= 1){
            int u = (i >= off) ? sb[i-off] : 0;
            __syncthreads();
            if (i >= off) sb[i] += u;
            __syncthreads();
        }
        if (idx < nb) counts[(size_t)t*nb + idx] = carry + sb[i] - v;  // exclusive
        int tot = sb[255];
        __syncthreads();
        carry += tot;
    }
    if (i == 0) digTot[t] = carry;
}

// ---------------- sort pass B2: scan digit totals -> bucket bases ----------------
__global__ void k_base2(const int* __restrict__ digTot, int* __restrict__ base257,
                        float* __restrict__ out_val, const float* __restrict__ bc)
{
    __shared__ int sb[256];
    int t = threadIdx.x;
    if (t == 0) *out_val = bc[0];
    int v = digTot[t];
    sb[t] = v; __syncthreads();
    for (int off = 1; off < 256; off <<= 1){
        int u = (t >= off) ? sb[t-off] : 0;
        __syncthreads();
        if (t >= off) sb[t] += u;
        __syncthreads();
    }
    base257[t] = sb[t] - v;
    if (t == 255) base257[256] = sb[t];
}

// ---------------- sort pass C: scatter into buckets (LDS cursors, no global atomics) ----------------
__global__ __launch_bounds__(256) void k_bucket(const int* __restrict__ ei, int e, int e2,
        const int* __restrict__ counts, int nbT, const int* __restrict__ base257,
        unsigned int* __restrict__ buck)
{
    __shared__ int curs[256];
    int t = threadIdx.x;
    curs[t] = counts[(size_t)t*nbT + blockIdx.x] + base257[t];
    __syncthreads();
    int base = blockIdx.x*TILE;
    #pragma unroll
    for (int k = 0; k < TILE/256; k++){
        int i = base + k*256 + t;
        if (i < e2){
            int s, d;
            if (i < e){ s = ei[i]; d = ei[(size_t)e + i]; }
            else      { s = i - e; d = i - e; }
            int p = atomicAdd(&curs[d >> 8], 1);
            buck[p] = ((unsigned int)d << 16) | (unsigned int)s;
        }
    }
}

// ---------------- sort pass D: per-bucket counting sort -> csr + rs/re ----------------
__global__ __launch_bounds__(256) void k_p2(const unsigned int* __restrict__ buck,
        const int* __restrict__ base257, int n,
        int* __restrict__ csr, int* __restrict__ rs, int* __restrict__ re)
{
    __shared__ int bins[256], sc[256], curs[256];
    const int b = blockIdx.x, t = threadIdx.x;
    const int lo = base257[b], hi = base257[b+1];
    bins[t] = 0; __syncthreads();
    for (int i = lo + t; i < hi; i += 256){
        int dg = (buck[i] >> 16) & 0xFF;
        atomicAdd(&bins[dg], 1);
    }
    __syncthreads();
    sc[t] = bins[t]; __syncthreads();
    for (int off = 1; off < 256; off <<= 1){
        int v = (t >= off) ? sc[t-off] : 0;
        __syncthreads();
        if (t >= off) sc[t] += v;
        __syncthreads();
    }
    int sInc = sc[t];
    int node = b*256 + t;
    if (node < n){
        rs[node] = lo + sInc - bins[t];
        re[node] = lo + sInc;
    }
    curs[t] = lo + sInc - bins[t];
    __syncthreads();
    for (int i = lo + t; i < hi; i += 256){
        unsigned int pk = buck[i];
        int p = atomicAdd(&curs[(pk >> 16) & 0xFF], 1);
        csr[p] = (int)(pk & 0xFFFFu);
    }
}

// ---------------- gemm1 (pure MFMA): h1b = bf16(x @ W1); fused a_s/a_d dots ----------------
__global__ __launch_bounds__(256) void k_gemm1(const float* __restrict__ x,
        const unsigned short* __restrict__ w1t,
        const float* __restrict__ aS, const float* __restrict__ aD,
        unsigned short* __restrict__ h1b, float* __restrict__ pAS, float* __restrict__ pAD, int n)
{
    __shared__ unsigned short As[64*136];   // 17.4 KB  [row][k] padded
    __shared__ unsigned short Bs[128*136];  // 34.8 KB  [n][k]  padded
    const int tid  = threadIdx.x;
    const int brow = blockIdx.x*64;

    // stage A: x fp32 -> bf16 LDS
    {
        int row = tid >> 2, cb = (tid & 3)*32;
        bool ok = brow + row < n;
        #pragma unroll
        for (int i=0;i<8;i++){
            float4 v = ok ? *(const float4*)&x[(size_t)(brow+row)*128 + cb + i*4]
                          : make_float4(0.f,0.f,0.f,0.f);
            ushort4 b = make_ushort4(f2bf(v.x),f2bf(v.y),f2bf(v.z),f2bf(v.w));
            *(ushort4*)&As[row*136 + cb + i*4] = b;
        }
    }
    // stage B: w1t bf16 [128][128] -> LDS
    {
        int nn = tid >> 1, kb = (tid & 1)*64;
        #pragma unroll
        for (int i=0;i<8;i++)
            *(uint4*)&Bs[nn*136 + kb + i*8] = *(const uint4*)&w1t[nn*128 + kb + i*8];
    }
    __syncthreads();

    const int wv = tid >> 6, lane = tid & 63;
    const int m = lane & 15, quad = lane >> 4;
    floatx4 acc[8];
    #pragma unroll
    for (int i=0;i<8;i++) acc[i] = (floatx4){0.f,0.f,0.f,0.f};

    #pragma unroll
    for (int kc=0; kc<4; kc++){
        int k0 = kc*32 + quad*8;
        short8 a = *(const short8*)&As[(wv*16+m)*136 + k0];
        #pragma unroll
        for (int ct=0; ct<8; ct++){
            short8 b = *(const short8*)&Bs[(ct*16+m)*136 + k0];
            acc[ct] = __builtin_amdgcn_mfma_f32_16x16x32_bf16(a, b, acc[ct], 0,0,0);
        }
    }
    __syncthreads();   // done reading As

    // repack C (bf16) into As as [64][128]
    #pragma unroll
    for (int ct=0; ct<8; ct++){
        #pragma unroll
        for (int r=0;r<4;r++){
            int row = wv*16 + quad*4 + r;
            As[row*128 + ct*16 + m] = f2bf(acc[ct][r]);
        }
    }
    __syncthreads();

    // coalesced global writes + per-(row,head) attention dots
    {
        int row = tid >> 2, hd = tid & 3;
        int grow = brow + row;
        if (grow < n){
            float ps=0.f, pd=0.f;
            #pragma unroll
            for (int i=0;i<4;i++){
                uint4 u = *(const uint4*)&As[row*128 + hd*32 + i*8];
                *(uint4*)&h1b[(size_t)grow*128 + hd*32 + i*8] = u;
                unsigned int uw[4] = {u.x,u.y,u.z,u.w};
                #pragma unroll
                for (int j=0;j<4;j++){
                    float c0 = bfx(uw[j]), c1 = bfy(uw[j]);
                    int cc = hd*32 + i*8 + j*2;
                    ps += c0*aS[cc] + c1*aS[cc+1];
                    pd += c0*aD[cc] + c1*aD[cc+1];
                }
            }
            pAS[grow*4+hd] = ps;
            pAD[grow*4+hd] = pd;
        }
    }
}

// ---------------- layer-1 aggregation: chunk-16, lane-parallel exp, 16-deep gather ----------------
__global__ __launch_bounds__(256) void k_agg1(const int* __restrict__ rs, const int* __restrict__ re,
        const int* __restrict__ csr, const float* __restrict__ as1, const float* __restrict__ ad1,
        const unsigned short* __restrict__ h1b, const float* __restrict__ b1,
        unsigned short* __restrict__ h1ob, int n)
{
    const int lane = threadIdx.x & 63;
    const int node = blockIdx.x*4 + (threadIdx.x >> 6);
    if (node >= n) return;
    const int h   = lane >> 4;
    const int f   = lane*2;
    const int j16 = lane & 15;
    const int grp = lane & 48;
    const float adv = ad1[node*4 + h];
    const int start = rs[node], end = re[node];
    const unsigned int* hp = (const unsigned int*)h1b + (f >> 1);  // index s*64

    float den = 0.f, ax = 0.f, ay = 0.f;
    int i0 = start;

    for (; i0 + 16 <= end; i0 += 16){
        int sj = csr[i0 + j16];
        float e = __expf(leaky02(as1[sj*4 + h] + adv));
        den += e;
        #pragma unroll
        for (int j = 0; j < 16; j++){
            float ej = __shfl(e,  grp + j, 64);
            int   s2 = __shfl(sj, grp + j, 64);
            unsigned int g = hp[s2*64];
            ax += ej*bfx(g); ay += ej*bfy(g);
        }
    }
    int c = end - i0;
    if (c > 0){
        int jj = (j16 < c) ? j16 : (c-1);
        int sj = csr[i0 + jj];
        float e = __expf(leaky02(as1[sj*4 + h] + adv));
        if (j16 < c) den += e;
        for (int j = 0; j < c; j += 4){
            #pragma unroll
            for (int u = 0; u < 4; u++){
                int je = j + u;
                int jc = (je < c) ? je : (c-1);
                float ej = __shfl(e,  grp + jc, 64);
                int   s2 = __shfl(sj, grp + jc, 64);
                ej = (je < c) ? ej : 0.f;
                unsigned int g = hp[s2*64];
                ax += ej*bfx(g); ay += ej*bfy(g);
            }
        }
    }
    den += __shfl_xor(den, 1, 64);
    den += __shfl_xor(den, 2, 64);
    den += __shfl_xor(den, 4, 64);
    den += __shfl_xor(den, 8, 64);

    float ox = ax/den + b1[f];
    float oy = ay/den + b1[f+1];
    ox = ox > 0.f ? ox : expm1f(ox);
    oy = oy > 0.f ? oy : expm1f(oy);
    unsigned int pk = (unsigned int)f2bf(ox) | ((unsigned int)f2bf(oy) << 16);
    *(unsigned int*)&h1ob[(size_t)node*128 + f] = pk;
}

// ---------------- gemm2 (MFMA): h2pb = bf16(h1ob @ W2); fused a_s/a_d ----------------
__global__ __launch_bounds__(256) void k_gemm2(const unsigned short* __restrict__ h1ob,
        const unsigned short* __restrict__ w2t,
        const float* __restrict__ aS, const float* __restrict__ aD,
        unsigned short* __restrict__ h2pb, float* __restrict__ pAS, float* __restrict__ pAD, int n)
{
    __shared__ unsigned short As[64*136];   // 17.4 KB
    __shared__ unsigned short Bs[32*136];   // 8.7 KB
    const int tid  = threadIdx.x;
    const int brow = blockIdx.x*64;

    {   // stage A (already bf16)
        int row = tid >> 2, cb = (tid & 3)*32;
        bool ok = brow + row < n;
        #pragma unroll
        for (int i=0;i<4;i++){
            uint4 v = ok ? *(const uint4*)&h1ob[(size_t)(brow+row)*128 + cb + i*8]
                         : make_uint4(0,0,0,0);
            *(uint4*)&As[row*136 + cb + i*8] = v;
        }
    }
    {   // stage B: w2t [32][128]
        int nn = tid >> 3, kb = (tid & 7)*16;
        *(uint4*)&Bs[nn*136 + kb]     = *(const uint4*)&w2t[nn*128 + kb];
        *(uint4*)&Bs[nn*136 + kb + 8] = *(const uint4*)&w2t[nn*128 + kb + 8];
    }
    __syncthreads();

    const int wv = tid >> 6, lane = tid & 63;
    const int m = lane & 15, quad = lane >> 4;
    floatx4 acc[2];
    acc[0] = (floatx4){0.f,0.f,0.f,0.f};
    acc[1] = (floatx4){0.f,0.f,0.f,0.f};

    #pragma unroll
    for (int kc=0; kc<4; kc++){
        int k0 = kc*32 + quad*8;
        short8 a = *(const short8*)&As[(wv*16+m)*136 + k0];
        #pragma unroll
        for (int ct=0; ct<2; ct++){
            short8 b = *(const short8*)&Bs[(ct*16+m)*136 + k0];
            acc[ct] = __builtin_amdgcn_mfma_f32_16x16x32_bf16(a, b, acc[ct], 0,0,0);
        }
    }
    __syncthreads();

    #pragma unroll
    for (int ct=0; ct<2; ct++){
        #pragma unroll
        for (int r=0;r<4;r++){
            int row = wv*16 + quad*4 + r;
            As[row*32 + ct*16 + m] = f2bf(acc[ct][r]);
        }
    }
    __syncthreads();

    if (tid < 64){
        int grow = brow + tid;
        if (grow < n){
            float ps=0.f, pd=0.f;
            #pragma unroll
            for (int i=0;i<4;i++){
                uint4 u = *(const uint4*)&As[tid*32 + i*8];
                *(uint4*)&h2pb[(size_t)grow*32 + i*8] = u;
                unsigned int uw[4] = {u.x,u.y,u.z,u.w};
                #pragma unroll
                for (int j=0;j<4;j++){
                    float c0 = bfx(uw[j]), c1 = bfy(uw[j]);
                    int cc = i*8 + j*2;
                    ps += c0*aS[cc] + c1*aS[cc+1];
                    pd += c0*aD[cc] + c1*aD[cc+1];
                }
            }
            pAS[grow] = ps;
            pAD[grow] = pd;
        }
    }
}

// ---------------- layer-2 aggregation: chunk-16, halves split payload edges ----------------
__global__ __launch_bounds__(256) void k_agg2(const int* __restrict__ rs, const int* __restrict__ re,
        const int* __restrict__ csr, const float* __restrict__ as2, const float* __restrict__ ad2,
        const unsigned short* __restrict__ h2pb, const float* __restrict__ b2,
        float* __restrict__ out, int n)
{
    const int lane = threadIdx.x & 63;
    const int node = blockIdx.x*4 + (threadIdx.x >> 6);
    if (node >= n) return;
    const int f    = lane & 31;
    const int half = lane >> 5;
    const int j16  = lane & 15;
    const int grp  = lane & 48;
    const float adv = ad2[node];
    const int start = rs[node], end = re[node];
    const unsigned short* hp = h2pb + f;

    float den = 0.f, acc = 0.f;
    int i0 = start;

    for (; i0 + 16 <= end; i0 += 16){
        int sj = csr[i0 + j16];
        float e = __expf(leaky02(as2[sj] + adv));
        den += e;
        #pragma unroll
        for (int jj = 0; jj < 8; jj++){
            int j = 2*jj + half;
            float ej = __shfl(e,  grp + j, 64);
            int   s2 = __shfl(sj, grp + j, 64);
            acc += ej * bf1(hp[s2*32]);
        }
    }
    int c = end - i0;
    if (c > 0){
        int jj = (j16 < c) ? j16 : (c-1);
        int sj = csr[i0 + jj];
        float e = __expf(leaky02(as2[sj] + adv));
        if (j16 < c) den += e;
        for (int j = half; j < c; j += 8){
            #pragma unroll
            for (int u = 0; u < 4; u++){
                int je = j + 2*u;
                int jc = (je < c) ? je : (c-1);
                float ej = __shfl(e,  grp + (jc & 15), 64);
                int   s2 = __shfl(sj, grp + (jc & 15), 64);
                ej = (je < c) ? ej : 0.f;
                acc += ej * bf1(hp[s2*32]);
            }
        }
    }
    den += __shfl_xor(den, 1, 64);
    den += __shfl_xor(den, 2, 64);
    den += __shfl_xor(den, 4, 64);
    den += __shfl_xor(den, 8, 64);
    acc += __shfl_xor(acc, 32, 64);

    if (half == 0){
        float o = acc/den + b2[f];
        o = o > 0.f ? o : expm1f(o);
        out[(size_t)node*32 + f] = o;
    }
}

// ---------------- heads: logits[A,N] (transposed store) + value mean ----------------
__global__ __launch_bounds__(256) void k_head(const float* __restrict__ h2, const float* __restrict__ Wa,
        const float* __restrict__ ba, const float* __restrict__ Wc, int n, float* __restrict__ out)
{
    __shared__ float WaS[1024];
    __shared__ float baS[32], WcS[32];
    int tid = threadIdx.x;
    *(float4*)&WaS[tid*4] = *(const float4*)&Wa[tid*4];
    if (tid < 32){ baS[tid] = ba[tid]; WcS[tid] = Wc[tid]; }
    __syncthreads();

    int nidx = blockIdx.x*256 + tid;
    bool act = nidx < n;
    float hv[32];
    #pragma unroll
    for (int j=0;j<8;j++){
        float4 v = act ? *(const float4*)&h2[(size_t)nidx*32 + j*4] : make_float4(0.f,0.f,0.f,0.f);
        hv[j*4+0]=v.x; hv[j*4+1]=v.y; hv[j*4+2]=v.z; hv[j*4+3]=v.w;
    }
    #pragma unroll
    for (int a=0;a<32;a++){
        float acc = baS[a];
        #pragma unroll
        for (int c=0;c<32;c++) acc += hv[c]*WaS[c*32+a];
        if (act) out[(size_t)a*n + nidx] = acc;
    }
    float v = 0.f;
    #pragma unroll
    for (int c=0;c<32;c++) v += hv[c]*WcS[c];
    #pragma unroll
    for (int msk=1; msk<64; msk<<=1) v += __shfl_xor(v, msk, 64);
    if ((tid & 63) == 0) atomicAdd(&out[(size_t)32*n], v*(1.0f/n));
}

extern "C" void kernel_launch(void* const* d_in, const int* in_sizes, int n_in,
                              void* d_out, int out_size, void* d_ws, size_t ws_size,
                              hipStream_t stream)
{
    const float* x   = (const float*)d_in[0];
    const int*   ei  = (const int*)d_in[1];
    const float* W1  = (const float*)d_in[2];
    const float* a1s = (const float*)d_in[3];
    const float* a1d = (const float*)d_in[4];
    const float* b1  = (const float*)d_in[5];
    const float* W2  = (const float*)d_in[6];
    const float* a2s = (const float*)d_in[7];
    const float* a2d = (const float*)d_in[8];
    const float* b2  = (const float*)d_in[9];
    const float* Wa  = (const float*)d_in[10];
    const float* ba  = (const float*)d_in[11];
    const float* Wc  = (const float*)d_in[12];
    const float* bc  = (const float*)d_in[13];
    float* out = (float*)d_out;

    const int N  = in_sizes[0] / 128;
    const int E  = in_sizes[1] / 2;
    const int E2 = E + N;
    const int nbT = (E2 + TILE - 1) / TILE;   // sort tiles
    const int nbB = (N + 255) / 256;          // buckets

    // workspace layout (256B-aligned chunks)
    char* base = (char*)d_ws;
    auto alloc = [&](size_t bytes) -> char* {
        char* p = base; base += (bytes + 255) & ~(size_t)255; return p;
    };
    float* h2     = (float*)alloc((size_t)N*32*4);
    float* as1    = (float*)alloc((size_t)N*4*4);
    float* ad1    = (float*)alloc((size_t)N*4*4);
    float* as2    = (float*)alloc((size_t)N*4);
    float* ad2    = (float*)alloc((size_t)N*4);
    int* counts   = (int*)alloc((size_t)nbT*256*4);
    int* digTot   = (int*)alloc(256*4);
    int* base257  = (int*)alloc(257*4);
    int* rs       = (int*)alloc((size_t)N*4);
    int* re       = (int*)alloc((size_t)N*4);
    int* csr      = (int*)alloc((size_t)E2*4);
    unsigned int* buck = (unsigned int*)alloc((size_t)E2*4);
    unsigned short* h1b  = (unsigned short*)alloc((size_t)N*128*2);
    unsigned short* h1ob = (unsigned short*)alloc((size_t)N*128*2);
    unsigned short* h2pb = (unsigned short*)alloc((size_t)N*32*2);
    unsigned short* w1t  = (unsigned short*)alloc(128*128*2);
    unsigned short* w2t  = (unsigned short*)alloc(32*128*2);

    const int nbN   = (N + 255) / 256;
    const int nbG   = (N + 63) / 64;
    const int nbAgg = (N + 3) / 4;

    k_prep<<<1, 256, 0, stream>>>(W1, W2, w1t, w2t);
    k_cnt<<<nbT, 256, 0, stream>>>(ei, E, E2, counts, nbT);
    k_scan_digit<<<256, 256, 0, stream>>>(counts, nbT, digTot);
    k_base2<<<1, 256, 0, stream>>>(digTot, base257, out + (size_t)32*N, bc);
    k_bucket<<<nbT, 256, 0, stream>>>(ei, E, E2, counts, nbT, base257, buck);
    k_p2<<<nbB, 256, 0, stream>>>(buck, base257, N, csr, rs, re);
    k_gemm1<<<nbG, 256, 0, stream>>>(x, w1t, a1s, a1d, h1b, as1, ad1, N);
    k_agg1<<<nbAgg, 256, 0, stream>>>(rs, re, csr, as1, ad1, h1b, b1, h1ob, N);
    k_gemm2<<<nbG, 256, 0, stream>>>(h1ob, w2t, a2s, a2d, h2pb, as2, ad2, N);
    k_agg2<<<nbAgg, 256, 0, stream>>>(rs, re, csr, as2, ad2, h2pb, b2, h2, N);
    k_head<<<nbN, 256, 0, stream>>>(h2, Wa, ba, Wc, N, out);
}